// Round 1
// baseline (150.769 us; speedup 1.0000x reference)
//
#include <hip/hip_runtime.h>
#include <math.h>

// Diffusion1D implicit step = tridiagonal solve with constant coefficients.
// r = D*dt/dx^2 = 0.1  ->  A^-1 decays as lambda^|i-j|, lambda ~= 0.0839.
// lambda^17 < fp32 ulp, so each x_i depends only on C[i-16 .. i+16].
// Interior: per-thread 16-output chunk, two register IIR scans (F fwd, B bwd),
//   x_i = G * (F_i + B_i - C_i),  G = 1/sqrt((1+2r)^2 - 4r^2).
// Boundaries (rows 0..39 and nx-40..nx-1): exact Thomas over a 65-row window
//   in one extra block (seed/image errors decay by lambda^25 ~ 1e-27).

constexpr int T    = 16;          // outputs per thread
constexpr int W    = 16;          // one-sided stencil half-width
constexpr int BLK  = 256;
constexpr int TILE = BLK * T;     // 4096 elements per interior block
constexpr int BW   = 40;          // boundary width handled by boundary block

__global__ __launch_bounds__(BLK)
void diff1d_kernel(const float* __restrict__ C,
                   const float* __restrict__ dtp,
                   const float* __restrict__ cSp,
                   const float* __restrict__ cBp,
                   float* __restrict__ out, int nx)
{
    // Mimic reference fp32 coefficient computation, then refine in double.
    float dtf = *dtp;
    float rf  = (1e-9f * dtf) / (1e-4f * 1e-4f);   // = 0.1 for dt=1
    double r    = (double)rf;
    double b0   = 1.0 + 2.0 * r;
    double disc = sqrt(b0 * b0 - 4.0 * r * r);
    float lam = (float)((b0 - disc) / (2.0 * r));  // ~0.08392
    float G   = (float)(1.0 / disc);               // ~0.84515

    int nb_int = gridDim.x - 1;                    // interior blocks

    if ((int)blockIdx.x < nb_int) {
        // ---------------- interior path ----------------
        int tile0 = blockIdx.x * TILE;
        int g0    = tile0 + (int)threadIdx.x * T;  // first output of this thread
        bool edge = (blockIdx.x == 0) || ((int)blockIdx.x == nb_int - 1);

        float v[T + 2 * W];                        // 48 floats: [g0-16, g0+32)
        if (!edge) {
            const float4* p = (const float4*)(C + (g0 - W)); // 64B-aligned
            #pragma unroll
            for (int q = 0; q < (T + 2 * W) / 4; ++q) {
                float4 f = p[q];
                v[4 * q + 0] = f.x; v[4 * q + 1] = f.y;
                v[4 * q + 2] = f.z; v[4 * q + 3] = f.w;
            }
        } else {
            #pragma unroll
            for (int k = 0; k < T + 2 * W; ++k) {
                int gi = g0 - W + k;
                gi = gi < 0 ? 0 : (gi > nx - 1 ? nx - 1 : gi);
                v[k] = C[gi];
            }
        }

        // forward IIR: F_i = sum_{k>=0} lam^k C[i-k] (truncated at 31 terms)
        float F = 0.f;
        float Freg[T];
        #pragma unroll
        for (int k = 0; k < W; ++k) F = fmaf(lam, F, v[k]);
        #pragma unroll
        for (int k = 0; k < T; ++k) { F = fmaf(lam, F, v[W + k]); Freg[k] = F; }

        // backward IIR + combine
        float B = 0.f;
        #pragma unroll
        for (int k = T + 2 * W - 1; k >= W + T; --k) B = fmaf(lam, B, v[k]);
        #pragma unroll
        for (int k = T - 1; k >= 0; --k) {
            B = fmaf(lam, B, v[W + k]);
            float x = G * (Freg[k] + B - v[W + k]);
            int i = g0 + k;
            if (!edge || (i >= BW && i <= nx - 1 - BW)) out[i] = x;
        }
    } else {
        // ---------------- boundary block (exact Thomas, tiny windows) ------
        __shared__ float cp_s[72], dp_s[72], dpr_s[72];
        float csurf = *cSp, cbulk = *cBp;
        float b0f = 1.0f + 2.0f * rf;

        if (threadIdx.x == 0) {
            // left boundary: exact forward sweep rows 0..64
            cp_s[0] = 0.f;       // row 0: b=1, c=0
            dp_s[0] = csurf;
            for (int j = 1; j <= 64; ++j) {
                float denom = b0f + rf * cp_s[j - 1];     // b - a*cp, a=-r
                cp_s[j] = -rf / denom;
                dp_s[j] = (C[j] + rf * dp_s[j - 1]) / denom;
            }
            // backward; seed error decays by lam^25 before reaching j<40
            float xx = dp_s[64];
            for (int j = 63; j >= 0; --j) {
                xx = dp_s[j] - cp_s[j] * xx;
                if (j < BW) out[j] = xx;
            }
        } else if (threadIdx.x == 64) {
            // right boundary: forward seeded 25 rows early (converged cp)
            float denomc = rf / lam;      // converged denominator
            int s = nx - 65;
            float dpp = 0.f;              // seed; error decays by lam^26
            for (int j = 0; j < 64; ++j) {            // rows s .. nx-2
                dpp = (C[s + j] + rf * dpp) / denomc;
                dpr_s[j] = dpp;
            }
            out[nx - 1] = cbulk;          // row nx-1: x = C_bulk exactly
            float xx = cbulk;
            for (int j = 63; j >= 1; --j) {           // rows nx-2 down
                xx = dpr_s[j] + lam * xx;             // x_j = dp_j - cp* x_{j+1}
                int jj = s + j;
                if (jj >= nx - BW) out[jj] = xx;
            }
        }
    }
}

extern "C" void kernel_launch(void* const* d_in, const int* in_sizes, int n_in,
                              void* d_out, int out_size, void* d_ws, size_t ws_size,
                              hipStream_t stream)
{
    const float* C   = (const float*)d_in[0];
    const float* dtp = (const float*)d_in[1];
    const float* cS  = (const float*)d_in[2];
    const float* cB  = (const float*)d_in[3];
    float* out = (float*)d_out;
    int nx = in_sizes[0];

    int nb = nx / TILE;   // NX = 2^23 is divisible by TILE=4096
    diff1d_kernel<<<nb + 1, BLK, 0, stream>>>(C, dtp, cS, cB, out, nx);
}

// Round 2
// 93.367 us; speedup vs baseline: 1.6148x; 1.6148x over previous
//
#include <hip/hip_runtime.h>
#include <math.h>

// Diffusion1D implicit step = tridiagonal solve with constant coefficients.
// r = D*dt/dx^2 = 0.1  ->  A^-1 decays as lambda^|i-j|, lambda ~= 0.0839.
// lambda^17 < fp32 ulp, so each x_i depends only on C[i-16 .. i+16].
// Interior: per-thread 16-output chunk, two register IIR scans (F fwd, B bwd),
//   x_i = G * (F_i + B_i - C_i),  G = 1/sqrt((1+2r)^2 - 4r^2).
// All global traffic is unit-stride float4 via an LDS round-trip (the R1
// version's per-thread-contiguous global accesses were 64B-lane-strided ->
// 64 cache lines per wave instruction -> TA-bound at 620 GB/s).
// Boundaries (rows 0..39 and nx-40..nx-1): exact Thomas over a 65-row window
// in one extra block (seed/image errors decay by lambda^25 ~ 1e-27).

constexpr int T    = 16;          // outputs per thread
constexpr int W    = 16;          // one-sided stencil half-width
constexpr int BLK  = 256;
constexpr int TILE = BLK * T;     // 4096 elements per interior block
constexpr int BW   = 40;          // boundary width handled by boundary block
constexpr int NG_IN = (TILE + 2 * W) / 4;   // 1032 input granules (float4)

// XOR bank swizzle on 16B granules: keeps every LDS phase <=2-way aliased.
__device__ __forceinline__ int swz(int g) { return g ^ ((g >> 3) & 7); }

__global__ __launch_bounds__(BLK)
void diff1d_kernel(const float* __restrict__ C,
                   const float* __restrict__ dtp,
                   const float* __restrict__ cSp,
                   const float* __restrict__ cBp,
                   float* __restrict__ out, int nx)
{
    float dtf = *dtp;
    float rf  = (1e-9f * dtf) / (1e-4f * 1e-4f);   // = 0.1 for dt=1
    double r    = (double)rf;
    double b0   = 1.0 + 2.0 * r;
    double disc = sqrt(b0 * b0 - 4.0 * r * r);
    float lam = (float)((b0 - disc) / (2.0 * r));  // ~0.08392
    float G   = (float)(1.0 / disc);               // ~0.84515

    int nb_int = gridDim.x - 1;                    // interior blocks

    if ((int)blockIdx.x < nb_int) {
        // ---------------- interior path ----------------
        __shared__ float4 s_in4[NG_IN];            // 16.5 KB
        __shared__ float4 s_out4[TILE / 4];        // 16 KB

        int tid   = threadIdx.x;
        int tile0 = blockIdx.x * TILE;
        bool edge = (blockIdx.x == 0) || ((int)blockIdx.x == nb_int - 1);

        // Phase A: coalesced stage of [tile0-16, tile0+TILE+16) into LDS
        if (!edge) {
            const float4* gsrc = (const float4*)(C + tile0 - W); // 64B aligned
            #pragma unroll
            for (int q = 0; q < 4; ++q) {
                int g = q * BLK + tid;
                s_in4[swz(g)] = gsrc[g];
            }
            if (tid < NG_IN - 4 * BLK) {           // 8 leftover granules
                int g = 4 * BLK + tid;
                s_in4[swz(g)] = gsrc[g];
            }
        } else {
            for (int j = tid; j < TILE + 2 * W; j += BLK) {
                int gi = tile0 - W + j;
                gi = gi < 0 ? 0 : (gi > nx - 1 ? nx - 1 : gi);
                ((float*)&s_in4[swz(j >> 2)])[j & 3] = C[gi];
            }
        }
        __syncthreads();

        // Phase B: per-thread 48-float window from LDS (granules 4t..4t+11)
        float v[T + 2 * W];
        #pragma unroll
        for (int j = 0; j < 12; ++j) {
            float4 f = s_in4[swz(4 * tid + j)];
            v[4 * j + 0] = f.x; v[4 * j + 1] = f.y;
            v[4 * j + 2] = f.z; v[4 * j + 3] = f.w;
        }

        // forward IIR: F_i = sum_{k>=0} lam^k C[i-k] (truncated at 31 terms)
        float F = 0.f;
        float Freg[T];
        #pragma unroll
        for (int k = 0; k < W; ++k) F = fmaf(lam, F, v[k]);
        #pragma unroll
        for (int k = 0; k < T; ++k) { F = fmaf(lam, F, v[W + k]); Freg[k] = F; }

        // backward IIR + combine (overwrite Freg with x to save VGPRs)
        float B = 0.f;
        #pragma unroll
        for (int k = T + 2 * W - 1; k >= W + T; --k) B = fmaf(lam, B, v[k]);
        #pragma unroll
        for (int k = T - 1; k >= 0; --k) {
            B = fmaf(lam, B, v[W + k]);
            Freg[k] = G * (Freg[k] + B - v[W + k]);
        }

        // Phase C: results to LDS (granules 4t..4t+3)
        #pragma unroll
        for (int q = 0; q < 4; ++q) {
            float4 f;
            f.x = Freg[4 * q + 0]; f.y = Freg[4 * q + 1];
            f.z = Freg[4 * q + 2]; f.w = Freg[4 * q + 3];
            s_out4[swz(4 * tid + q)] = f;
        }
        __syncthreads();

        // Phase D: coalesced store
        if (!edge) {
            float4* gdst = (float4*)(out + tile0);
            #pragma unroll
            for (int q = 0; q < 4; ++q) {
                int g = q * BLK + tid;
                gdst[g] = s_out4[swz(g)];
            }
        } else {
            for (int j = tid; j < TILE; j += BLK) {
                int i = tile0 + j;
                if (i >= BW && i <= nx - 1 - BW)
                    out[i] = ((const float*)&s_out4[swz(j >> 2)])[j & 3];
            }
        }
    } else {
        // ---------------- boundary block (exact Thomas, tiny windows) ------
        __shared__ float cp_s[72], dp_s[72], dpr_s[72];
        float csurf = *cSp, cbulk = *cBp;
        float b0f = 1.0f + 2.0f * rf;

        if (threadIdx.x == 0) {
            // left boundary: exact forward sweep rows 0..64
            cp_s[0] = 0.f;       // row 0: b=1, c=0
            dp_s[0] = csurf;
            for (int j = 1; j <= 64; ++j) {
                float denom = b0f + rf * cp_s[j - 1];     // b - a*cp, a=-r
                cp_s[j] = -rf / denom;
                dp_s[j] = (C[j] + rf * dp_s[j - 1]) / denom;
            }
            // backward; seed error decays by lam^25 before reaching j<40
            float xx = dp_s[64];
            for (int j = 63; j >= 0; --j) {
                xx = dp_s[j] - cp_s[j] * xx;
                if (j < BW) out[j] = xx;
            }
        } else if (threadIdx.x == 64) {
            // right boundary: forward seeded 25 rows early (converged cp)
            float denomc = rf / lam;      // converged denominator
            int s = nx - 65;
            float dpp = 0.f;              // seed; error decays by lam^26
            for (int j = 0; j < 64; ++j) {            // rows s .. nx-2
                dpp = (C[s + j] + rf * dpp) / denomc;
                dpr_s[j] = dpp;
            }
            out[nx - 1] = cbulk;          // row nx-1: x = C_bulk exactly
            float xx = cbulk;
            for (int j = 63; j >= 1; --j) {           // rows nx-2 down
                xx = dpr_s[j] + lam * xx;             // x_j = dp_j - cp* x_{j+1}
                int jj = s + j;
                if (jj >= nx - BW) out[jj] = xx;
            }
        }
    }
}

extern "C" void kernel_launch(void* const* d_in, const int* in_sizes, int n_in,
                              void* d_out, int out_size, void* d_ws, size_t ws_size,
                              hipStream_t stream)
{
    const float* C   = (const float*)d_in[0];
    const float* dtp = (const float*)d_in[1];
    const float* cS  = (const float*)d_in[2];
    const float* cB  = (const float*)d_in[3];
    float* out = (float*)d_out;
    int nx = in_sizes[0];

    int nb = nx / TILE;   // NX = 2^23 is divisible by TILE=4096
    diff1d_kernel<<<nb + 1, BLK, 0, stream>>>(C, dtp, cS, cB, out, nx);
}

// Round 3
// 90.219 us; speedup vs baseline: 1.6711x; 1.0349x over previous
//
#include <hip/hip_runtime.h>
#include <math.h>

// Diffusion1D implicit step = tridiagonal solve with constant coefficients.
// r = D*dt/dx^2 = 0.1  ->  A^-1 decays as lambda^|i-j|, lambda ~= 0.0839.
// lambda^9 ~ 2e-10 < fp32 ulp, so each x_i depends only on C[i-8 .. i+8].
// Interior: per-thread 16-output chunk, two register IIR scans (F fwd, B bwd),
//   x_i = G * (F_i + B_i - C_i),  G = 1/sqrt((1+2r)^2 - 4r^2).
// All global traffic is unit-stride float4 via an LDS round-trip (per-thread
// contiguous global access is 64B-lane-strided -> TA-bound at 620 GB/s, R1).
// R3: W 16->8 (-33% FMA, 12->8 ds_read_b128) and single in-place LDS buffer
// (32.5 -> 16.1 KB -> ~2x blocks/CU) to hide VALU behind the HBM stream.
// Boundaries (rows 0..39 and nx-40..nx-1): exact Thomas over a 65-row window
// in one extra block (seed/image errors decay by lambda^25 ~ 1e-27).

constexpr int T    = 16;          // outputs per thread
constexpr int W    = 8;           // one-sided stencil half-width
constexpr int BLK  = 256;
constexpr int TILE = BLK * T;     // 4096 elements per interior block
constexpr int BW   = 40;          // boundary width handled by boundary block
constexpr int NWIN = T + 2 * W;   // 32-float window per thread
constexpr int NG   = (TILE + 2 * W) / 4;   // 1028 staged granules (float4)

// XOR bank swizzle on 16B granules: keeps every LDS phase <=2-way aliased.
__device__ __forceinline__ int swz(int g) { return g ^ ((g >> 3) & 7); }

__global__ __launch_bounds__(BLK)
void diff1d_kernel(const float* __restrict__ C,
                   const float* __restrict__ dtp,
                   const float* __restrict__ cSp,
                   const float* __restrict__ cBp,
                   float* __restrict__ out, int nx)
{
    float dtf = *dtp;
    float rf  = (1e-9f * dtf) / (1e-4f * 1e-4f);   // = 0.1 for dt=1
    double r    = (double)rf;
    double b0   = 1.0 + 2.0 * r;
    double disc = sqrt(b0 * b0 - 4.0 * r * r);
    float lam = (float)((b0 - disc) / (2.0 * r));  // ~0.08392
    float G   = (float)(1.0 / disc);               // ~0.84515

    int nb_int = gridDim.x - 1;                    // interior blocks

    if ((int)blockIdx.x < nb_int) {
        // ---------------- interior path ----------------
        __shared__ float4 s4[NG];                  // 16.1 KB, in-place reuse

        int tid   = threadIdx.x;
        int tile0 = blockIdx.x * TILE;
        bool edge = (blockIdx.x == 0) || ((int)blockIdx.x == nb_int - 1);

        // Phase A: coalesced stage of [tile0-8, tile0+TILE+8) into LDS
        if (!edge) {
            const float4* gsrc = (const float4*)(C + tile0 - W); // 32B aligned
            #pragma unroll
            for (int q = 0; q < 4; ++q) {
                int g = q * BLK + tid;
                s4[swz(g)] = gsrc[g];
            }
            if (tid < NG - 4 * BLK) {              // 4 leftover granules
                int g = 4 * BLK + tid;
                s4[swz(g)] = gsrc[g];
            }
        } else {
            for (int j = tid; j < TILE + 2 * W; j += BLK) {
                int gi = tile0 - W + j;
                gi = gi < 0 ? 0 : (gi > nx - 1 ? nx - 1 : gi);
                ((float*)&s4[swz(j >> 2)])[j & 3] = C[gi];
            }
        }
        __syncthreads();

        // Phase B: per-thread 32-float window from LDS (granules 4t..4t+7)
        float v[NWIN];
        #pragma unroll
        for (int j = 0; j < NWIN / 4; ++j) {
            float4 f = s4[swz(4 * tid + j)];
            v[4 * j + 0] = f.x; v[4 * j + 1] = f.y;
            v[4 * j + 2] = f.z; v[4 * j + 3] = f.w;
        }

        // forward IIR: F_i = sum_{k>=0} lam^k C[i-k] (truncated)
        float F = 0.f;
        float Freg[T];
        #pragma unroll
        for (int k = 0; k < W; ++k) F = fmaf(lam, F, v[k]);
        #pragma unroll
        for (int k = 0; k < T; ++k) { F = fmaf(lam, F, v[W + k]); Freg[k] = F; }

        // backward IIR + combine (overwrite Freg with x to save VGPRs)
        float B = 0.f;
        #pragma unroll
        for (int k = NWIN - 1; k >= W + T; --k) B = fmaf(lam, B, v[k]);
        #pragma unroll
        for (int k = T - 1; k >= 0; --k) {
            B = fmaf(lam, B, v[W + k]);
            Freg[k] = G * (Freg[k] + B - v[W + k]);
        }
        __syncthreads();   // all reads done before in-place overwrite

        // Phase C: results back into the same buffer (granules 4t+2..4t+5)
        #pragma unroll
        for (int q = 0; q < 4; ++q) {
            float4 f;
            f.x = Freg[4 * q + 0]; f.y = Freg[4 * q + 1];
            f.z = Freg[4 * q + 2]; f.w = Freg[4 * q + 3];
            s4[swz(4 * tid + W / 4 + q)] = f;
        }
        __syncthreads();

        // Phase D: coalesced store (output granule g sits at staged g + W/4)
        if (!edge) {
            float4* gdst = (float4*)(out + tile0);
            #pragma unroll
            for (int q = 0; q < 4; ++q) {
                int g = q * BLK + tid;
                gdst[g] = s4[swz(g + W / 4)];
            }
        } else {
            for (int j = tid; j < TILE; j += BLK) {
                int i = tile0 + j;
                if (i >= BW && i <= nx - 1 - BW)
                    out[i] = ((const float*)&s4[swz((j + W) >> 2)])[j & 3];
            }
        }
    } else {
        // ---------------- boundary block (exact Thomas, tiny windows) ------
        __shared__ float cp_s[72], dp_s[72], dpr_s[72];
        float csurf = *cSp, cbulk = *cBp;
        float b0f = 1.0f + 2.0f * rf;

        if (threadIdx.x == 0) {
            // left boundary: exact forward sweep rows 0..64
            cp_s[0] = 0.f;       // row 0: b=1, c=0
            dp_s[0] = csurf;
            for (int j = 1; j <= 64; ++j) {
                float denom = b0f + rf * cp_s[j - 1];     // b - a*cp, a=-r
                cp_s[j] = -rf / denom;
                dp_s[j] = (C[j] + rf * dp_s[j - 1]) / denom;
            }
            // backward; seed error decays by lam^25 before reaching j<40
            float xx = dp_s[64];
            for (int j = 63; j >= 0; --j) {
                xx = dp_s[j] - cp_s[j] * xx;
                if (j < BW) out[j] = xx;
            }
        } else if (threadIdx.x == 64) {
            // right boundary: forward seeded 25 rows early (converged cp)
            float denomc = rf / lam;      // converged denominator
            int s = nx - 65;
            float dpp = 0.f;              // seed; error decays by lam^26
            for (int j = 0; j < 64; ++j) {            // rows s .. nx-2
                dpp = (C[s + j] + rf * dpp) / denomc;
                dpr_s[j] = dpp;
            }
            out[nx - 1] = cbulk;          // row nx-1: x = C_bulk exactly
            float xx = cbulk;
            for (int j = 63; j >= 1; --j) {           // rows nx-2 down
                xx = dpr_s[j] + lam * xx;             // x_j = dp_j - cp* x_{j+1}
                int jj = s + j;
                if (jj >= nx - BW) out[jj] = xx;
            }
        }
    }
}

extern "C" void kernel_launch(void* const* d_in, const int* in_sizes, int n_in,
                              void* d_out, int out_size, void* d_ws, size_t ws_size,
                              hipStream_t stream)
{
    const float* C   = (const float*)d_in[0];
    const float* dtp = (const float*)d_in[1];
    const float* cS  = (const float*)d_in[2];
    const float* cB  = (const float*)d_in[3];
    float* out = (float*)d_out;
    int nx = in_sizes[0];

    int nb = nx / TILE;   // NX = 2^23 is divisible by TILE=4096
    diff1d_kernel<<<nb + 1, BLK, 0, stream>>>(C, dtp, cS, cB, out, nx);
}